// Round 2
// baseline (549.581 us; speedup 1.0000x reference)
//
#include <hip/hip_runtime.h>
#include <hip/hip_bf16.h>

// RelativePositionEncoding: O[i,j,c] = Wt[dres][c] + Wt[66+dtok][c]
//                                    + same_entity*Wt[132][c] + Wt[133+dchain][c]
// Wt[b][c] = W[c*139 + b]. Pure gather+add; store-BW bound (537 MB fp32 out).
// Output dtype is FP32 (reference W is fp32) — R0 failed by writing bf16.

#define R_MAX 32
#define NO_BINS 139
#define C_Z 128
#define C_HALF 64

__global__ __launch_bounds__(256) void relpos_kernel(
    const int* __restrict__ asym, const int* __restrict__ res,
    const int* __restrict__ ent,  const int* __restrict__ tok,
    const int* __restrict__ sym,  const float* __restrict__ W,
    float* __restrict__ out, int N)
{
    // Transposed half of W: lds[b*64 + c_local] = W[(c_off+c_local)*139 + b]
    __shared__ float lds[NO_BINS * C_HALF];   // 35,584 B -> 4 blocks/CU
    const int tid   = threadIdx.x;
    const int c_off = blockIdx.x * C_HALF;
    const int i     = blockIdx.y;

    for (int idx = tid; idx < NO_BINS * C_HALF; idx += 256) {
        const int b = idx >> 6;
        const int c = idx & 63;
        // gather (stride 556B) but W is 71KB -> L1/L2 resident; writes conflict-free
        lds[idx] = W[(size_t)(c_off + c) * NO_BINS + b];
    }
    __syncthreads();

    // i-side scalars (uniform per block -> scalar loads)
    const int ai = asym[i], ri = res[i], ei = ent[i], ti = tok[i], si = sym[i];

    const int c8 = (tid & 7) * 8;   // lane's 8-float slice within the c-half
    const int jl = tid >> 3;        // 0..31: j within chunk

    // entity column's c-slice is fixed per lane -> keep in registers
    const float4 entLo = *(const float4*)&lds[132 * C_HALF + c8];
    const float4 entHi = *(const float4*)&lds[132 * C_HALF + c8 + 4];

    for (int jb = 0; jb < N; jb += 32) {
        const int j = jb + jl;
        if (j >= N) break;
        const int rj = res[j], tj = tok[j], aj = asym[j], ej = ent[j], sj = sym[j];

        const bool sc  = (ai == aj);
        const bool sr  = (ri == rj);
        const bool seB = (ei == ej);

        int dr = ri - rj + R_MAX;
        dr = min(max(dr, 0), 2 * R_MAX);
        if (!sc) dr = 2 * R_MAX + 1;          // 65

        int dt = ti - tj + R_MAX;
        dt = min(max(dt, 0), 2 * R_MAX);
        if (!(sc && sr)) dt = 2 * R_MAX + 1;  // 65

        int dc = si - sj + 2;
        dc = min(max(dc, 0), 4);
        if (!seB) dc = 5;

        const float se = seB ? 1.0f : 0.0f;

        const float* pr = &lds[dr * C_HALF + c8];
        const float* pt = &lds[(66 + dt) * C_HALF + c8];
        const float* pc = &lds[(133 + dc) * C_HALF + c8];

        const float4 r0 = *(const float4*)pr,       r1 = *(const float4*)(pr + 4);
        const float4 t0 = *(const float4*)pt,       t1 = *(const float4*)(pt + 4);
        const float4 k0 = *(const float4*)pc,       k1 = *(const float4*)(pc + 4);

        float4 o0, o1;
        o0.x = fmaf(se, entLo.x, r0.x + t0.x + k0.x);
        o0.y = fmaf(se, entLo.y, r0.y + t0.y + k0.y);
        o0.z = fmaf(se, entLo.z, r0.z + t0.z + k0.z);
        o0.w = fmaf(se, entLo.w, r0.w + t0.w + k0.w);
        o1.x = fmaf(se, entHi.x, r1.x + t1.x + k1.x);
        o1.y = fmaf(se, entHi.y, r1.y + t1.y + k1.y);
        o1.z = fmaf(se, entHi.z, r1.z + t1.z + k1.z);
        o1.w = fmaf(se, entHi.w, r1.w + t1.w + k1.w);

        // 32B per lane, 8 lanes/j -> 256B contiguous per j, aligned
        float* po = out + ((size_t)i * N + j) * C_Z + c_off + c8;
        *(float4*)(po)     = o0;
        *(float4*)(po + 4) = o1;
    }
}

extern "C" void kernel_launch(void* const* d_in, const int* in_sizes, int n_in,
                              void* d_out, int out_size, void* d_ws, size_t ws_size,
                              hipStream_t stream) {
    const int*   asym = (const int*)d_in[0];
    const int*   res  = (const int*)d_in[1];
    const int*   ent  = (const int*)d_in[2];
    const int*   tok  = (const int*)d_in[3];
    const int*   sym  = (const int*)d_in[4];
    const float* W    = (const float*)d_in[5];
    float* out = (float*)d_out;

    const int N = in_sizes[0];  // B = 1
    dim3 grid(C_Z / C_HALF, N);
    relpos_kernel<<<grid, 256, 0, stream>>>(asym, res, ent, tok, sym, W, out, N);
}